// Round 1
// baseline (111.667 us; speedup 1.0000x reference)
//
#include <hip/hip_runtime.h>
#include <math.h>

// Output depends ONLY on q_params (d_in[9]), q_basis (d_in[10]), fc3_w (d_in[11]),
// fc3_b (d_in[12]). The conv/fc tower in the reference is dead code (its result
// is used only for batch-size shape). Every output row is the same (p, 1-p).

struct c32 { float x, y; };

__device__ __forceinline__ void apply1q(c32* a, int mask,
                                        c32 u00, c32 u01, c32 u10, c32 u11) {
#pragma unroll
    for (int s = 0; s < 16; ++s) {
        if (s & mask) continue;
        c32 a0 = a[s];
        c32 a1 = a[s | mask];
        c32 n0, n1;
        n0.x = u00.x * a0.x - u00.y * a0.y + u01.x * a1.x - u01.y * a1.y;
        n0.y = u00.x * a0.y + u00.y * a0.x + u01.x * a1.y + u01.y * a1.x;
        n1.x = u10.x * a0.x - u10.y * a0.y + u11.x * a1.x - u11.y * a1.y;
        n1.y = u10.x * a0.y + u10.y * a0.x + u11.x * a1.y + u11.y * a1.x;
        a[s] = n0;
        a[s | mask] = n1;
    }
}

__device__ __forceinline__ void rot3(c32* a, int w, float tx, float ty, float tz) {
    const int mask = 8 >> w;  // axis w is the (3-w)-th bit (C-order, axis 0 most significant)
    float sx, cx, sy, cy, sz, cz;
    sincosf(0.5f * tx, &sx, &cx);
    // RX = [[c, -i s], [-i s, c]]
    apply1q(a, mask, {cx, 0.f}, {0.f, -sx}, {0.f, -sx}, {cx, 0.f});
    sincosf(0.5f * ty, &sy, &cy);
    // RY = [[c, -s], [s, c]]
    apply1q(a, mask, {cy, 0.f}, {-sy, 0.f}, {sy, 0.f}, {cy, 0.f});
    sincosf(0.5f * tz, &sz, &cz);
    // RZ = diag(e^{-it/2}, e^{+it/2})
    apply1q(a, mask, {cz, -sz}, {0.f, 0.f}, {0.f, 0.f}, {cz, sz});
}

__device__ __forceinline__ void cnot(c32* a, int w) {
    const int cm = 8 >> w;       // control bit mask (axis w)
    const int tm = 8 >> (w + 1); // target bit mask (axis w+1)
#pragma unroll
    for (int s = 0; s < 16; ++s) {
        if ((s & cm) && !(s & tm)) {
            c32 t = a[s];
            a[s] = a[s | tm];
            a[s | tm] = t;
        }
    }
}

__global__ void __launch_bounds__(256)
qhbc_kernel(const float* __restrict__ q_params,  // [DEPTH=2][NQ=4][3]
            const float* __restrict__ q_basis,   // [NQ=4][3]
            const float* __restrict__ fc3_w,     // [1][4]
            const float* __restrict__ fc3_b,     // [1]
            float* __restrict__ out,             // [B][2]
            int n_rows) {
    // --- 16-amplitude state-vector simulation, fully in registers ---
    c32 a[16];
#pragma unroll
    for (int i = 0; i < 16; ++i) a[i] = {0.f, 0.f};
    a[0] = {1.f, 0.f};

#pragma unroll
    for (int w = 0; w < 4; ++w)
        rot3(a, w, q_basis[w * 3 + 0], q_basis[w * 3 + 1], q_basis[w * 3 + 2]);

#pragma unroll
    for (int l = 0; l < 2; ++l) {
#pragma unroll
        for (int w = 0; w < 4; ++w) {
            const int base = (l * 4 + w) * 3;
            rot3(a, w, q_params[base + 0], q_params[base + 1], q_params[base + 2]);
        }
#pragma unroll
        for (int w = 0; w < 3; ++w) cnot(a, w);
    }

    // Z-expectation per qubit: ev[w] = P(bit_w=0) - P(bit_w=1)
    float ev0 = 0.f, ev1 = 0.f, ev2 = 0.f, ev3 = 0.f;
#pragma unroll
    for (int s = 0; s < 16; ++s) {
        const float p = a[s].x * a[s].x + a[s].y * a[s].y;
        ev0 += (s & 8) ? -p : p;
        ev1 += (s & 4) ? -p : p;
        ev2 += (s & 2) ? -p : p;
        ev3 += (s & 1) ? -p : p;
    }

    const float logit = ev0 * fc3_w[0] + ev1 * fc3_w[1] + ev2 * fc3_w[2] +
                        ev3 * fc3_w[3] + fc3_b[0];
    const float p = 1.f / (1.f + expf(-logit));

    const int i = blockIdx.x * blockDim.x + threadIdx.x;
    if (i < n_rows) {
        float2* o = reinterpret_cast<float2*>(out);
        o[i] = make_float2(p, 1.f - p);
    }
}

extern "C" void kernel_launch(void* const* d_in, const int* in_sizes, int n_in,
                              void* d_out, int out_size, void* d_ws, size_t ws_size,
                              hipStream_t stream) {
    const float* q_params = (const float*)d_in[9];   // [2,4,3]
    const float* q_basis  = (const float*)d_in[10];  // [4,3]
    const float* fc3_w    = (const float*)d_in[11];  // [1,4]
    const float* fc3_b    = (const float*)d_in[12];  // [1]
    float* out = (float*)d_out;                      // [B,2] float32

    const int n_rows = out_size / 2;  // B = 1024
    const int block = 256;
    const int grid = (n_rows + block - 1) / block;
    qhbc_kernel<<<grid, block, 0, stream>>>(q_params, q_basis, fc3_w, fc3_b, out, n_rows);
}